// Round 2
// baseline (4478.357 us; speedup 1.0000x reference)
//
#include <hip/hip_runtime.h>
#include <math.h>

#define D_MODEL 256
#define NH 8
#define NL 4
#define NP 4
#define DH 32
#define LQ 10105
#define BATCH 2
#define NLAYERS 6
#define NTOK (BATCH * LQ)   // 20210

// ---------------------------------------------------------------------------
// Flatten: (B, D, H, W) -> (B, HW, D) slice of src_flat / pos_flat, + level emb
// ---------------------------------------------------------------------------
__global__ __launch_bounds__(256)
void flatten_k(const float* __restrict__ src, const float* __restrict__ pos,
               const float* __restrict__ lvl, float* __restrict__ src_flat,
               float* __restrict__ pos_flat, int HW, int start)
{
    int hw = blockIdx.x;
    int b  = blockIdx.y;
    int d  = threadIdx.x;
    float sv = src[((size_t)b * D_MODEL + d) * HW + hw];
    float pv = pos[((size_t)b * D_MODEL + d) * HW + hw];
    size_t o = ((size_t)(b * LQ + start + hw)) * D_MODEL + d;
    src_flat[o] = sv + lvl[d];
    pos_flat[o] = pv;
}

// ---------------------------------------------------------------------------
// fp32 tiled GEMM: C[M,N] = (A (+A2))[M,K] @ W[K,N] + bias (+Res) (ReLU opt)
// 128x64 tile, BK=16, 256 threads, 8x4 per thread. All LDS reads float4.
// ---------------------------------------------------------------------------
template<bool HAS_A2, bool RELU, bool HAS_RES>
__global__ __launch_bounds__(256)
void gemm_k(const float* __restrict__ A, const float* __restrict__ A2,
            const float* __restrict__ Wt, const float* __restrict__ bias,
            const float* __restrict__ Res, float* __restrict__ C,
            int M, int N, int K)
{
    __shared__ float As[16][132];  // [k][m], stride 132 keeps float4 align, pad vs conflicts
    __shared__ float Bs[16][64];   // [k][n]

    int tid = threadIdx.x;
    int m0 = blockIdx.x * 128;
    int n0 = blockIdx.y * 64;
    int tx = tid & 15;        // n dir (4 cols each)
    int ty = tid >> 4;        // m dir (8 rows each)

    int a_row  = tid >> 1;          // 0..127
    int a_col  = (tid & 1) * 8;     // 0 or 8
    int b_row  = tid >> 4;          // 0..15
    int b_col  = (tid & 15) * 4;    // 0..60

    int arow_g = m0 + a_row;
    bool a_ok = (arow_g < M);

    float acc[8][4] = {};

    for (int kt = 0; kt < K; kt += 16) {
        float4 av0 = make_float4(0.f, 0.f, 0.f, 0.f);
        float4 av1 = make_float4(0.f, 0.f, 0.f, 0.f);
        if (a_ok) {
            const float* ap = &A[(size_t)arow_g * K + kt + a_col];
            av0 = *(const float4*)ap;
            av1 = *(const float4*)(ap + 4);
            if (HAS_A2) {
                const float* ap2 = &A2[(size_t)arow_g * K + kt + a_col];
                float4 t0 = *(const float4*)ap2;
                float4 t1 = *(const float4*)(ap2 + 4);
                av0.x += t0.x; av0.y += t0.y; av0.z += t0.z; av0.w += t0.w;
                av1.x += t1.x; av1.y += t1.y; av1.z += t1.z; av1.w += t1.w;
            }
        }
        float4 bv = *(const float4*)&Wt[(size_t)(kt + b_row) * N + n0 + b_col];

        __syncthreads();
        As[a_col + 0][a_row] = av0.x;
        As[a_col + 1][a_row] = av0.y;
        As[a_col + 2][a_row] = av0.z;
        As[a_col + 3][a_row] = av0.w;
        As[a_col + 4][a_row] = av1.x;
        As[a_col + 5][a_row] = av1.y;
        As[a_col + 6][a_row] = av1.z;
        As[a_col + 7][a_row] = av1.w;
        *(float4*)&Bs[b_row][b_col] = bv;
        __syncthreads();

        #pragma unroll
        for (int kk = 0; kk < 16; ++kk) {
            float4 a0 = *(const float4*)&As[kk][ty * 8];
            float4 a1 = *(const float4*)&As[kk][ty * 8 + 4];
            float4 bb = *(const float4*)&Bs[kk][tx * 4];
            const float a[8] = {a0.x, a0.y, a0.z, a0.w, a1.x, a1.y, a1.z, a1.w};
            const float bj[4] = {bb.x, bb.y, bb.z, bb.w};
            #pragma unroll
            for (int i = 0; i < 8; ++i)
                #pragma unroll
                for (int j = 0; j < 4; ++j)
                    acc[i][j] += a[i] * bj[j];
        }
    }

    int col = n0 + tx * 4;
    float4 bsv = *(const float4*)&bias[col];
    #pragma unroll
    for (int i = 0; i < 8; ++i) {
        int row = m0 + ty * 8 + i;
        if (row >= M) continue;
        float4 r;
        r.x = acc[i][0] + bsv.x;
        r.y = acc[i][1] + bsv.y;
        r.z = acc[i][2] + bsv.z;
        r.w = acc[i][3] + bsv.w;
        if (HAS_RES) {
            float4 rv = *(const float4*)&Res[(size_t)row * N + col];
            r.x += rv.x; r.y += rv.y; r.z += rv.z; r.w += rv.w;
        }
        if (RELU) {
            r.x = fmaxf(r.x, 0.f); r.y = fmaxf(r.y, 0.f);
            r.z = fmaxf(r.z, 0.f); r.w = fmaxf(r.w, 0.f);
        }
        *(float4*)&C[(size_t)row * N + col] = r;
    }
}

// ---------------------------------------------------------------------------
// Deformable sampling: one block per (q, b); 256 threads = 8 heads x 32 chans
// ---------------------------------------------------------------------------
__global__ __launch_bounds__(256)
void sample_k(const float* __restrict__ val, const float* __restrict__ off,
              const float* __restrict__ logits, float* __restrict__ out)
{
    const int Hs[4] = {76, 38, 19, 10};
    const int Ws[4] = {100, 50, 25, 13};
    const int ST[4] = {0, 7600, 9500, 9975};

    int q = blockIdx.x;
    int b = blockIdx.y;
    int tid = threadIdx.x;

    __shared__ float s_px[128], s_py[128], s_w[128];

    int lq, local;
    if (q < 7600)      { lq = 0; local = q; }
    else if (q < 9500) { lq = 1; local = q - 7600; }
    else if (q < 9975) { lq = 2; local = q - 9500; }
    else               { lq = 3; local = q - 9975; }
    int Wq = Ws[lq], Hq = Hs[lq];
    int ry = local / Wq, rx = local - ry * Wq;
    float refx = (rx + 0.5f) / (float)Wq;
    float refy = (ry + 0.5f) / (float)Hq;

    if (tid < 128) {
        int h = tid >> 4, pt = tid & 15;
        int l = pt >> 2, p = pt & 3;
        const float* ob = &off[((size_t)(b * LQ + q)) * 256 + h * 32 + l * 8 + p * 2];
        float ox = ob[0], oy = ob[1];
        s_px[tid] = refx * (float)Ws[l] + ox - 0.5f;
        s_py[tid] = refy * (float)Hs[l] + oy - 0.5f;
        s_w[tid]  = logits[((size_t)(b * LQ + q)) * 128 + h * 16 + pt];
    }
    __syncthreads();
    if (tid < 8) {
        float mx = -1e30f;
        #pragma unroll
        for (int i = 0; i < 16; ++i) mx = fmaxf(mx, s_w[tid * 16 + i]);
        float sum = 0.f;
        #pragma unroll
        for (int i = 0; i < 16; ++i) {
            float e = expf(s_w[tid * 16 + i] - mx);
            s_w[tid * 16 + i] = e;
            sum += e;
        }
        float inv = 1.0f / sum;
        #pragma unroll
        for (int i = 0; i < 16; ++i) s_w[tid * 16 + i] *= inv;
    }
    __syncthreads();

    int h = tid >> 5, d = tid & 31;
    const float* vb = val + ((size_t)b * LQ) * 256 + h * 32 + d;
    float acc = 0.f;

    #pragma unroll
    for (int pt = 0; pt < 16; ++pt) {
        int l = pt >> 2;
        int W = Ws[l], H = Hs[l], st = ST[l];
        float px = s_px[h * 16 + pt];
        float py = s_py[h * 16 + pt];
        float w  = s_w[h * 16 + pt];
        float x0f = floorf(px), y0f = floorf(py);
        float lx = px - x0f, ly = py - y0f;
        int x0 = (int)x0f, y0 = (int)y0f;
        int x1 = x0 + 1, y1 = y0 + 1;
        float w00 = w * (1.f - ly) * (1.f - lx);
        float w01 = w * (1.f - ly) * lx;
        float w10 = w * ly * (1.f - lx);
        float w11 = w * ly * lx;
        bool vx0 = (x0 >= 0) & (x0 < W);
        bool vx1 = (x1 >= 0) & (x1 < W);
        bool vy0 = (y0 >= 0) & (y0 < H);
        bool vy1 = (y1 >= 0) & (y1 < H);
        if (vy0 & vx0) acc += w00 * vb[(size_t)(st + y0 * W + x0) * 256];
        if (vy0 & vx1) acc += w01 * vb[(size_t)(st + y0 * W + x1) * 256];
        if (vy1 & vx0) acc += w10 * vb[(size_t)(st + y1 * W + x0) * 256];
        if (vy1 & vx1) acc += w11 * vb[(size_t)(st + y1 * W + x1) * 256];
    }
    out[((size_t)(b * LQ + q)) * 256 + tid] = acc;
}

// ---------------------------------------------------------------------------
// LayerNorm over D=256, one block per row
// ---------------------------------------------------------------------------
__global__ __launch_bounds__(256)
void ln_k(const float* __restrict__ x, const float* __restrict__ g,
          const float* __restrict__ bt, float* __restrict__ out)
{
    int row = blockIdx.x;
    int d = threadIdx.x;
    float v = x[(size_t)row * 256 + d];

    __shared__ float red[4];
    __shared__ float s_mean, s_rstd;

    float s = v;
    #pragma unroll
    for (int o = 32; o > 0; o >>= 1) s += __shfl_down(s, o, 64);
    int wave = d >> 6, lane = d & 63;
    if (lane == 0) red[wave] = s;
    __syncthreads();
    if (d == 0) s_mean = (red[0] + red[1] + red[2] + red[3]) * (1.0f / 256.0f);
    __syncthreads();
    float m = s_mean;
    float c = v - m;
    float s2 = c * c;
    #pragma unroll
    for (int o = 32; o > 0; o >>= 1) s2 += __shfl_down(s2, o, 64);
    if (lane == 0) red[wave] = s2;
    __syncthreads();
    if (d == 0) s_rstd = rsqrtf((red[0] + red[1] + red[2] + red[3]) * (1.0f / 256.0f) + 1e-5f);
    __syncthreads();
    out[(size_t)row * 256 + d] = c * s_rstd * g[d] + bt[d];
}

// ---------------------------------------------------------------------------
extern "C" void kernel_launch(void* const* d_in, const int* in_sizes, int n_in,
                              void* d_out, int out_size, void* d_ws, size_t ws_size,
                              hipStream_t stream)
{
    const float* src_in[4] = {(const float*)d_in[0], (const float*)d_in[2],
                              (const float*)d_in[4], (const float*)d_in[6]};
    const float* pos_in[4] = {(const float*)d_in[1], (const float*)d_in[3],
                              (const float*)d_in[5], (const float*)d_in[7]};
    const float* lvl    = (const float*)d_in[8];
    const float* w_off  = (const float*)d_in[9];
    const float* b_off  = (const float*)d_in[10];
    const float* w_attn = (const float*)d_in[11];
    const float* b_attn = (const float*)d_in[12];
    const float* w_val  = (const float*)d_in[13];
    const float* b_val  = (const float*)d_in[14];
    const float* w_out  = (const float*)d_in[15];
    const float* b_out  = (const float*)d_in[16];
    const float* ln1_g  = (const float*)d_in[17];
    const float* ln1_b  = (const float*)d_in[18];
    const float* w_ffn1 = (const float*)d_in[19];
    const float* b_ffn1 = (const float*)d_in[20];
    const float* w_ffn2 = (const float*)d_in[21];
    const float* b_ffn2 = (const float*)d_in[22];
    const float* ln2_g  = (const float*)d_in[23];
    const float* ln2_b  = (const float*)d_in[24];

    float* ws   = (float*)d_ws;
    float* src  = ws;                              // NTOK*256
    float* pos  = src  + (size_t)NTOK * 256;       // NTOK*256
    float* valb = pos  + (size_t)NTOK * 256;       // NTOK*256 (also tmp pre-LN)
    float* offb = valb + (size_t)NTOK * 256;       // NTOK*256
    float* logb = offb + (size_t)NTOK * 256;       // NTOK*128
    float* samp = logb + (size_t)NTOK * 128;       // NTOK*256
    float* ffnb = samp + (size_t)NTOK * 256;       // NTOK*1024

    const int HWs[4] = {7600, 1900, 475, 130};
    const int ST[4]  = {0, 7600, 9500, 9975};
    for (int l = 0; l < 4; ++l) {
        dim3 g(HWs[l], BATCH);
        flatten_k<<<g, 256, 0, stream>>>(src_in[l], pos_in[l], lvl + l * 256,
                                         src, pos, HWs[l], ST[l]);
    }

    const int M = NTOK;
    const int MB = (M + 127) / 128;   // 158
    dim3 blk(256);

    for (int i = 0; i < NLAYERS; ++i) {
        const float* wv  = w_val  + (size_t)i * 256 * 256;
        const float* bv  = b_val  + (size_t)i * 256;
        const float* wo  = w_off  + (size_t)i * 256 * 256;
        const float* bo  = b_off  + (size_t)i * 256;
        const float* wa  = w_attn + (size_t)i * 256 * 128;
        const float* ba  = b_attn + (size_t)i * 128;
        const float* wou = w_out  + (size_t)i * 256 * 256;
        const float* bou = b_out  + (size_t)i * 256;
        const float* l1g = ln1_g  + (size_t)i * 256;
        const float* l1b = ln1_b  + (size_t)i * 256;
        const float* wf1 = w_ffn1 + (size_t)i * 256 * 1024;
        const float* bf1 = b_ffn1 + (size_t)i * 1024;
        const float* wf2 = w_ffn2 + (size_t)i * 1024 * 256;
        const float* bf2 = b_ffn2 + (size_t)i * 256;
        const float* l2g = ln2_g  + (size_t)i * 256;
        const float* l2b = ln2_b  + (size_t)i * 256;

        // value = src @ w_val + b_val
        gemm_k<false, false, false><<<dim3(MB, 4), blk, 0, stream>>>(
            src, nullptr, wv, bv, nullptr, valb, M, 256, 256);
        // off = (src+pos) @ w_off + b_off
        gemm_k<true, false, false><<<dim3(MB, 4), blk, 0, stream>>>(
            src, pos, wo, bo, nullptr, offb, M, 256, 256);
        // logits = (src+pos) @ w_attn + b_attn
        gemm_k<true, false, false><<<dim3(MB, 2), blk, 0, stream>>>(
            src, pos, wa, ba, nullptr, logb, M, 128, 256);
        // deformable sampling -> samp (B,LQ,NH,DH)
        sample_k<<<dim3(LQ, BATCH), blk, 0, stream>>>(valb, offb, logb, samp);
        // attn_out = samp @ w_out + b_out + src  -> valb (pre-LN)
        gemm_k<false, false, true><<<dim3(MB, 4), blk, 0, stream>>>(
            samp, nullptr, wou, bou, src, valb, M, 256, 256);
        // LN1 -> src
        ln_k<<<dim3(M), blk, 0, stream>>>(valb, l1g, l1b, src);
        // ffn1 = relu(src @ w_ffn1 + b_ffn1) -> ffnb
        gemm_k<false, true, false><<<dim3(MB, 16), blk, 0, stream>>>(
            src, nullptr, wf1, bf1, nullptr, ffnb, M, 1024, 256);
        // ffn2 = ffnb @ w_ffn2 + b_ffn2 + src -> valb (pre-LN)
        gemm_k<false, false, true><<<dim3(MB, 4), blk, 0, stream>>>(
            ffnb, nullptr, wf2, bf2, src, valb, M, 256, 1024);
        // LN2 -> src (or d_out on last layer)
        float* dst = (i == NLAYERS - 1) ? (float*)d_out : src;
        ln_k<<<dim3(M), blk, 0, stream>>>(valb, l2g, l2b, dst);
    }
}

// Round 3
// 3072.584 us; speedup vs baseline: 1.4575x; 1.4575x over previous
//
#include <hip/hip_runtime.h>
#include <math.h>

#define LQ 10105
#define BATCH 2
#define NLAYERS 6
#define NTOK (BATCH * LQ)   // 20210

typedef __attribute__((ext_vector_type(8))) short bf16x8;   // 8 bf16 (4 VGPRs)
typedef __attribute__((ext_vector_type(4))) float f32x4;

__device__ inline unsigned short f2bf_rne(float f) {
    unsigned u = __float_as_uint(f);
    unsigned r = u + 0x7fffu + ((u >> 16) & 1u);
    return (unsigned short)(r >> 16);
}
__device__ inline float bf2f(unsigned short h) {
    return __uint_as_float((unsigned)h << 16);
}

// ---------------------------------------------------------------------------
// Flatten: (B, D, H, W) -> (B, HW, D) slices, + level embed on src
// ---------------------------------------------------------------------------
__global__ __launch_bounds__(256)
void flatten_k(const float* __restrict__ src, const float* __restrict__ pos,
               const float* __restrict__ lvl, float* __restrict__ src_flat,
               float* __restrict__ pos_flat, int HW, int start)
{
    int hw = blockIdx.x;
    int b  = blockIdx.y;
    int d  = threadIdx.x;
    float sv = src[((size_t)b * 256 + d) * HW + hw];
    float pv = pos[((size_t)b * 256 + d) * HW + hw];
    size_t o = ((size_t)(b * LQ + start + hw)) * 256 + d;
    src_flat[o] = sv + lvl[d];
    pos_flat[o] = pv;
}

// ---------------------------------------------------------------------------
// Weight transpose + bf16 hi/lo split: W[L][K][N] fp32 -> Th/Tl[L][N][K] bf16
// ---------------------------------------------------------------------------
__global__ __launch_bounds__(256)
void wsplit_k(const float* __restrict__ W, unsigned short* __restrict__ Th,
              unsigned short* __restrict__ Tl, int K, int N,
              long srcStride, long dstStride)
{
    __shared__ float t[32][33];
    int layer = blockIdx.z;
    int n0 = blockIdx.x * 32, k0 = blockIdx.y * 32;
    int tx = threadIdx.x & 31, ty = threadIdx.x >> 5;   // tx: 0..31, ty: 0..7
    const float* Wsrc = W + (size_t)layer * srcStride;
    #pragma unroll
    for (int i = 0; i < 4; ++i)
        t[ty + i * 8][tx] = Wsrc[(size_t)(k0 + ty + i * 8) * N + n0 + tx];
    __syncthreads();
    unsigned short* th = Th + (size_t)layer * dstStride;
    unsigned short* tl = Tl + (size_t)layer * dstStride;
    #pragma unroll
    for (int i = 0; i < 4; ++i) {
        int n = n0 + ty + i * 8;
        float v = t[tx][ty + i * 8];
        unsigned short h = f2bf_rne(v);
        th[(size_t)n * K + k0 + tx] = h;
        tl[(size_t)n * K + k0 + tx] = f2bf_rne(v - bf2f(h));
    }
}

// concat b_off|b_attn -> boa[L][384]
__global__ void boa_k(const float* __restrict__ b_off,
                      const float* __restrict__ b_attn, float* __restrict__ boa)
{
    int l = blockIdx.x, t = threadIdx.x;
    boa[l * 384 + t] = (t < 256) ? b_off[l * 256 + t] : b_attn[l * 128 + (t - 256)];
}

// ---------------------------------------------------------------------------
// bf16x3 split MFMA GEMM: C[M,N] = (A(+A2))[M,K] @ B[K,N] + bias (+Res)(ReLU)
// B pre-transposed/split: Bh/Bl are [N][K] bf16. Tile 128x128x32, 4 waves.
// MFMA 16x16x32_bf16; A-frag: row=l&15, k=(l>>4)*8+j; C/D: col=l&15,
// row=(l>>4)*4+reg  [verified layout, learn_hip m89/m91].
// ---------------------------------------------------------------------------
template<bool HAS_A2, bool RELU, bool HAS_RES>
__global__ __launch_bounds__(256)
void gemm_mfma(const float* __restrict__ A, const float* __restrict__ A2,
               const unsigned short* __restrict__ Bh,
               const unsigned short* __restrict__ Bl,
               const float* __restrict__ bias, const float* __restrict__ Res,
               float* __restrict__ C, int M, int N, int K)
{
    __shared__ unsigned short sAh[128 * 32];   // [m][k], 64B rows
    __shared__ unsigned short sAl[128 * 32];
    __shared__ unsigned short sBh[128 * 32];   // [n][k]
    __shared__ unsigned short sBl[128 * 32];

    const int tid = threadIdx.x;
    const int m0 = blockIdx.x * 128;
    const int n0 = blockIdx.y * 128;

    const int w  = tid >> 6;           // wave 0..3
    const int l  = tid & 63;
    const int wm = (w >> 1) * 64;      // wave row offset
    const int wn = (w & 1) * 64;       // wave col offset
    const int lr = l & 15;
    const int kb = (l >> 4) * 8;       // k base within 32
    const int rr = (l >> 4) * 4;       // C row base within 16

    const int sm = tid >> 1;           // staging row/col 0..127
    const int sk = (tid & 1) * 16;     // staging k offset (16 elems)
    const int arow = m0 + sm;
    const bool aok = arow < M;

    f32x4 acc[4][4];
    #pragma unroll
    for (int i = 0; i < 4; ++i)
        #pragma unroll
        for (int j = 0; j < 4; ++j)
            acc[i][j] = (f32x4){0.f, 0.f, 0.f, 0.f};

    for (int kt = 0; kt < K; kt += 32) {
        // ---- load A (16 fp32) and B (16+16 bf16) to regs
        float va[16];
        if (aok) {
            const float* ap = &A[(size_t)arow * K + kt + sk];
            *(float4*)&va[0]  = *(const float4*)(ap + 0);
            *(float4*)&va[4]  = *(const float4*)(ap + 4);
            *(float4*)&va[8]  = *(const float4*)(ap + 8);
            *(float4*)&va[12] = *(const float4*)(ap + 12);
            if (HAS_A2) {
                const float* ap2 = &A2[(size_t)arow * K + kt + sk];
                float4 t0 = *(const float4*)(ap2 + 0);
                float4 t1 = *(const float4*)(ap2 + 4);
                float4 t2 = *(const float4*)(ap2 + 8);
                float4 t3 = *(const float4*)(ap2 + 12);
                va[0] += t0.x; va[1] += t0.y; va[2]  += t0.z; va[3]  += t0.w;
                va[4] += t1.x; va[5] += t1.y; va[6]  += t1.z; va[7]  += t1.w;
                va[8] += t2.x; va[9] += t2.y; va[10] += t2.z; va[11] += t2.w;
                va[12]+= t3.x; va[13]+= t3.y; va[14] += t3.z; va[15] += t3.w;
            }
        } else {
            #pragma unroll
            for (int j = 0; j < 16; ++j) va[j] = 0.f;
        }
        const unsigned short* bph = &Bh[(size_t)(n0 + sm) * K + kt + sk];
        const unsigned short* bpl = &Bl[(size_t)(n0 + sm) * K + kt + sk];
        bf16x8 vbh0 = *(const bf16x8*)(bph);
        bf16x8 vbh1 = *(const bf16x8*)(bph + 8);
        bf16x8 vbl0 = *(const bf16x8*)(bpl);
        bf16x8 vbl1 = *(const bf16x8*)(bpl + 8);

        // ---- convert/split A
        bf16x8 ah0, ah1, al0, al1;
        #pragma unroll
        for (int j = 0; j < 8; ++j) {
            float v0 = va[j], v1 = va[8 + j];
            unsigned short h0 = f2bf_rne(v0);
            unsigned short h1 = f2bf_rne(v1);
            ah0[j] = (short)h0;
            ah1[j] = (short)h1;
            al0[j] = (short)f2bf_rne(v0 - bf2f(h0));
            al1[j] = (short)f2bf_rne(v1 - bf2f(h1));
        }

        __syncthreads();   // previous iteration consumers done
        *(bf16x8*)&sAh[sm * 32 + sk]     = ah0;
        *(bf16x8*)&sAh[sm * 32 + sk + 8] = ah1;
        *(bf16x8*)&sAl[sm * 32 + sk]     = al0;
        *(bf16x8*)&sAl[sm * 32 + sk + 8] = al1;
        *(bf16x8*)&sBh[sm * 32 + sk]     = vbh0;
        *(bf16x8*)&sBh[sm * 32 + sk + 8] = vbh1;
        *(bf16x8*)&sBl[sm * 32 + sk]     = vbl0;
        *(bf16x8*)&sBl[sm * 32 + sk + 8] = vbl1;
        __syncthreads();

        // ---- fragments + MFMA
        bf16x8 fah[4], fal[4];
        #pragma unroll
        for (int mf = 0; mf < 4; ++mf) {
            int off = (wm + mf * 16 + lr) * 32 + kb;
            fah[mf] = *(const bf16x8*)&sAh[off];
            fal[mf] = *(const bf16x8*)&sAl[off];
        }
        #pragma unroll
        for (int nf = 0; nf < 4; ++nf) {
            int boff = (wn + nf * 16 + lr) * 32 + kb;
            bf16x8 fbh = *(const bf16x8*)&sBh[boff];
            bf16x8 fbl = *(const bf16x8*)&sBl[boff];
            #pragma unroll
            for (int mf = 0; mf < 4; ++mf) {
                f32x4 c = acc[mf][nf];
                c = __builtin_amdgcn_mfma_f32_16x16x32_bf16(fah[mf], fbh, c, 0, 0, 0);
                c = __builtin_amdgcn_mfma_f32_16x16x32_bf16(fah[mf], fbl, c, 0, 0, 0);
                c = __builtin_amdgcn_mfma_f32_16x16x32_bf16(fal[mf], fbh, c, 0, 0, 0);
                acc[mf][nf] = c;
            }
        }
    }

    // ---- epilogue
    #pragma unroll
    for (int nf = 0; nf < 4; ++nf) {
        int col = n0 + wn + nf * 16 + lr;
        float bs = bias[col];
        #pragma unroll
        for (int mf = 0; mf < 4; ++mf) {
            int rowb = m0 + wm + mf * 16 + rr;
            #pragma unroll
            for (int r = 0; r < 4; ++r) {
                int row = rowb + r;
                if (row < M) {
                    float v = acc[mf][nf][r] + bs;
                    if (HAS_RES) v += Res[(size_t)row * N + col];
                    if (RELU) v = fmaxf(v, 0.f);
                    C[(size_t)row * N + col] = v;
                }
            }
        }
    }
}

// ---------------------------------------------------------------------------
// Deformable sampling: block per (q,b). Phase A (128 thr): softmax via 16-lane
// shuffle groups + fused corner weights/indices -> LDS. Phase B (256 thr =
// 8 heads x 32 ch): 4 gathers+FMA per point off broadcast LDS.
// ---------------------------------------------------------------------------
__global__ __launch_bounds__(256)
void sample_k(const float* __restrict__ val, const float* __restrict__ oab,
              float* __restrict__ out)
{
    const int Hs[4] = {76, 38, 19, 10};
    const int Ws[4] = {100, 50, 25, 13};
    const int ST[4] = {0, 7600, 9500, 9975};

    int q = blockIdx.x;
    int b = blockIdx.y;
    int tid = threadIdx.x;

    __shared__ int2 s_iw[512];   // (idx, weight-bits) per (h,pt,corner)

    if (tid < 128) {
        int h = tid >> 4, pt = tid & 15, lvl = pt >> 2, p = pt & 3;
        int lq, local;
        if (q < 7600)      { lq = 0; local = q; }
        else if (q < 9500) { lq = 1; local = q - 7600; }
        else if (q < 9975) { lq = 2; local = q - 9500; }
        else               { lq = 3; local = q - 9975; }
        int Wq = Ws[lq], Hq = Hs[lq];
        int ry = local / Wq, rx = local - ry * Wq;
        float refx = (rx + 0.5f) / (float)Wq;
        float refy = (ry + 0.5f) / (float)Hq;

        size_t rowb = (size_t)(b * LQ + q) * 384;
        float logit = oab[rowb + 256 + h * 16 + pt];
        float mx = logit;
        mx = fmaxf(mx, __shfl_xor(mx, 1, 64));
        mx = fmaxf(mx, __shfl_xor(mx, 2, 64));
        mx = fmaxf(mx, __shfl_xor(mx, 4, 64));
        mx = fmaxf(mx, __shfl_xor(mx, 8, 64));
        float e = expf(logit - mx);
        float s = e;
        s += __shfl_xor(s, 1, 64);
        s += __shfl_xor(s, 2, 64);
        s += __shfl_xor(s, 4, 64);
        s += __shfl_xor(s, 8, 64);
        float aw = e / s;

        float ox = oab[rowb + h * 32 + lvl * 8 + p * 2];
        float oy = oab[rowb + h * 32 + lvl * 8 + p * 2 + 1];
        int W = Ws[lvl], H = Hs[lvl], st = ST[lvl];
        float px = refx * (float)W + ox - 0.5f;
        float py = refy * (float)H + oy - 0.5f;
        float x0f = floorf(px), y0f = floorf(py);
        float lx = px - x0f, ly = py - y0f;
        int x0 = (int)x0f, y0 = (int)y0f;
        int x1 = x0 + 1, y1 = y0 + 1;
        float ax0 = ((x0 >= 0) & (x0 < W)) ? (1.f - lx) : 0.f;
        float ax1 = ((x1 >= 0) & (x1 < W)) ? lx : 0.f;
        float ay0 = ((y0 >= 0) & (y0 < H)) ? (1.f - ly) : 0.f;
        float ay1 = ((y1 >= 0) & (y1 < H)) ? ly : 0.f;
        int cx0 = min(max(x0, 0), W - 1), cx1 = min(max(x1, 0), W - 1);
        int cy0 = min(max(y0, 0), H - 1), cy1 = min(max(y1, 0), H - 1);
        int i00 = st + cy0 * W + cx0, i01 = st + cy0 * W + cx1;
        int i10 = st + cy1 * W + cx0, i11 = st + cy1 * W + cx1;
        int base4 = tid * 4;
        s_iw[base4 + 0] = make_int2(i00, __float_as_int(aw * ay0 * ax0));
        s_iw[base4 + 1] = make_int2(i01, __float_as_int(aw * ay0 * ax1));
        s_iw[base4 + 2] = make_int2(i10, __float_as_int(aw * ay1 * ax0));
        s_iw[base4 + 3] = make_int2(i11, __float_as_int(aw * ay1 * ax1));
    }
    __syncthreads();

    int h = tid >> 5, d = tid & 31;
    const float* vb = val + (size_t)(b * LQ) * 256 + h * 32 + d;
    float acc = 0.f;
    #pragma unroll
    for (int pt = 0; pt < 16; ++pt) {
        int base = (h * 16 + pt) * 4;
        #pragma unroll
        for (int c = 0; c < 4; ++c) {
            int2 iw = s_iw[base + c];
            float wgt = __int_as_float(iw.y);
            if (wgt != 0.f) acc += wgt * vb[(size_t)iw.x * 256];
        }
    }
    out[(size_t)(b * LQ + q) * 256 + tid] = acc;
}

// ---------------------------------------------------------------------------
// LayerNorm over D=256, one block per row
// ---------------------------------------------------------------------------
__global__ __launch_bounds__(256)
void ln_k(const float* __restrict__ x, const float* __restrict__ g,
          const float* __restrict__ bt, float* __restrict__ out)
{
    int row = blockIdx.x;
    int d = threadIdx.x;
    float v = x[(size_t)row * 256 + d];

    __shared__ float red[4];
    __shared__ float s_mean, s_rstd;

    float s = v;
    #pragma unroll
    for (int o = 32; o > 0; o >>= 1) s += __shfl_down(s, o, 64);
    int wave = d >> 6, lane = d & 63;
    if (lane == 0) red[wave] = s;
    __syncthreads();
    if (d == 0) s_mean = (red[0] + red[1] + red[2] + red[3]) * (1.0f / 256.0f);
    __syncthreads();
    float m = s_mean;
    float c = v - m;
    float s2 = c * c;
    #pragma unroll
    for (int o = 32; o > 0; o >>= 1) s2 += __shfl_down(s2, o, 64);
    if (lane == 0) red[wave] = s2;
    __syncthreads();
    if (d == 0) s_rstd = rsqrtf((red[0] + red[1] + red[2] + red[3]) * (1.0f / 256.0f) + 1e-5f);
    __syncthreads();
    out[(size_t)row * 256 + d] = c * s_rstd * g[d] + bt[d];
}

// ---------------------------------------------------------------------------
extern "C" void kernel_launch(void* const* d_in, const int* in_sizes, int n_in,
                              void* d_out, int out_size, void* d_ws, size_t ws_size,
                              hipStream_t stream)
{
    const float* src_in[4] = {(const float*)d_in[0], (const float*)d_in[2],
                              (const float*)d_in[4], (const float*)d_in[6]};
    const float* pos_in[4] = {(const float*)d_in[1], (const float*)d_in[3],
                              (const float*)d_in[5], (const float*)d_in[7]};
    const float* lvl    = (const float*)d_in[8];
    const float* w_off  = (const float*)d_in[9];
    const float* b_off  = (const float*)d_in[10];
    const float* w_attn = (const float*)d_in[11];
    const float* b_attn = (const float*)d_in[12];
    const float* w_val  = (const float*)d_in[13];
    const float* b_val  = (const float*)d_in[14];
    const float* w_out  = (const float*)d_in[15];
    const float* b_out  = (const float*)d_in[16];
    const float* ln1_g  = (const float*)d_in[17];
    const float* ln1_b  = (const float*)d_in[18];
    const float* w_ffn1 = (const float*)d_in[19];
    const float* b_ffn1 = (const float*)d_in[20];
    const float* w_ffn2 = (const float*)d_in[21];
    const float* b_ffn2 = (const float*)d_in[22];
    const float* ln2_g  = (const float*)d_in[23];
    const float* ln2_b  = (const float*)d_in[24];

    // ---- workspace layout (floats then bf16 weight area) ----
    float* ws    = (float*)d_ws;
    float* src   = ws;                              // NTOK*256
    float* pos   = src   + (size_t)NTOK * 256;      // NTOK*256
    float* preln = pos   + (size_t)NTOK * 256;      // NTOK*256
    float* uni   = preln + (size_t)NTOK * 256;      // NTOK*1024 union region
    float* valb  = uni;                             // NTOK*256   (phase 1)
    float* oab   = uni + (size_t)NTOK * 256;        // NTOK*384   (phase 1)
    float* samp  = oab + (size_t)NTOK * 384;        // NTOK*256   (phase 1)
    float* ffnb  = uni;                             // NTOK*1024  (phase 2)
    float* boa   = uni + (size_t)NTOK * 1024;       // 6*384
    unsigned short* Wh = (unsigned short*)(boa + 6 * 384);
    const long WL = 753664;                         // per-layer bf16 elems
    unsigned short* Wl = Wh + (size_t)NLAYERS * WL;
    // per-layer matrix offsets in Wh/Wl:
    const long O_VAL = 0, O_OFF = 65536, O_ATT = 131072, O_OUT = 163840,
               O_F1 = 229376, O_F2 = 491520;

    // ---- weight prep (every call; static content) ----
    wsplit_k<<<dim3(8, 8, 6),  256, 0, stream>>>(w_val,  Wh + O_VAL, Wl + O_VAL, 256, 256,  65536, WL);
    wsplit_k<<<dim3(8, 8, 6),  256, 0, stream>>>(w_off,  Wh + O_OFF, Wl + O_OFF, 256, 256,  65536, WL);
    wsplit_k<<<dim3(4, 8, 6),  256, 0, stream>>>(w_attn, Wh + O_ATT, Wl + O_ATT, 256, 128,  32768, WL);
    wsplit_k<<<dim3(8, 8, 6),  256, 0, stream>>>(w_out,  Wh + O_OUT, Wl + O_OUT, 256, 256,  65536, WL);
    wsplit_k<<<dim3(32, 8, 6), 256, 0, stream>>>(w_ffn1, Wh + O_F1,  Wl + O_F1,  256, 1024, 262144, WL);
    wsplit_k<<<dim3(8, 32, 6), 256, 0, stream>>>(w_ffn2, Wh + O_F2,  Wl + O_F2,  1024, 256, 262144, WL);
    boa_k<<<dim3(6), dim3(384), 0, stream>>>(b_off, b_attn, boa);

    const int HWs[4] = {7600, 1900, 475, 130};
    const int STt[4] = {0, 7600, 9500, 9975};
    for (int l = 0; l < 4; ++l) {
        dim3 g(HWs[l], BATCH);
        flatten_k<<<g, 256, 0, stream>>>(src_in[l], pos_in[l], lvl + l * 256,
                                         src, pos, HWs[l], STt[l]);
    }

    const int MB = (NTOK + 127) / 128;   // 158
    dim3 blk(256);

    for (int i = 0; i < NLAYERS; ++i) {
        const unsigned short* whL = Wh + (size_t)i * WL;
        const unsigned short* wlL = Wl + (size_t)i * WL;
        const float* bv  = b_val  + (size_t)i * 256;
        const float* bou = b_out  + (size_t)i * 256;
        const float* l1g = ln1_g  + (size_t)i * 256;
        const float* l1b = ln1_b  + (size_t)i * 256;
        const float* bf1 = b_ffn1 + (size_t)i * 1024;
        const float* bf2 = b_ffn2 + (size_t)i * 256;
        const float* l2g = ln2_g  + (size_t)i * 256;
        const float* l2b = ln2_b  + (size_t)i * 256;

        // value = src @ w_val + b_val
        gemm_mfma<false, false, false><<<dim3(MB, 2), blk, 0, stream>>>(
            src, nullptr, whL + O_VAL, wlL + O_VAL, bv, nullptr, valb, NTOK, 256, 256);
        // [off|attn] = (src+pos) @ [w_off|w_attn] + [b_off|b_attn]   (N=384 fused)
        gemm_mfma<true, false, false><<<dim3(MB, 3), blk, 0, stream>>>(
            src, pos, whL + O_OFF, wlL + O_OFF, boa + (size_t)i * 384, nullptr,
            oab, NTOK, 384, 256);
        // deformable sampling -> samp
        sample_k<<<dim3(LQ, BATCH), blk, 0, stream>>>(valb, oab, samp);
        // attn_out = samp @ w_out + b_out + src -> preln
        gemm_mfma<false, false, true><<<dim3(MB, 2), blk, 0, stream>>>(
            samp, nullptr, whL + O_OUT, wlL + O_OUT, bou, src, preln, NTOK, 256, 256);
        // LN1 -> src
        ln_k<<<dim3(NTOK), blk, 0, stream>>>(preln, l1g, l1b, src);
        // ffn1 = relu(src @ w_ffn1 + b_ffn1) -> ffnb (overwrites union)
        gemm_mfma<false, true, false><<<dim3(MB, 8), blk, 0, stream>>>(
            src, nullptr, whL + O_F1, wlL + O_F1, bf1, nullptr, ffnb, NTOK, 1024, 256);
        // ffn2 = ffnb @ w_ffn2 + b_ffn2 + src -> preln
        gemm_mfma<false, false, true><<<dim3(MB, 2), blk, 0, stream>>>(
            ffnb, nullptr, whL + O_F2, wlL + O_F2, bf2, src, preln, NTOK, 256, 1024);
        // LN2 -> src (or d_out on last layer)
        float* dst = (i == NLAYERS - 1) ? (float*)d_out : src;
        ln_k<<<dim3(NTOK), blk, 0, stream>>>(preln, l2g, l2b, dst);
    }
}

// Round 4
// 1922.070 us; speedup vs baseline: 2.3300x; 1.5986x over previous
//
#include <hip/hip_runtime.h>
#include <math.h>

#define LQ 10105
#define BATCH 2
#define NLAYERS 6
#define NTOK (BATCH * LQ)   // 20210

typedef __attribute__((ext_vector_type(8))) short bf16x8;   // 8 bf16 (4 VGPRs)
typedef __attribute__((ext_vector_type(4))) float f32x4;

__device__ inline unsigned short f2bf_rne(float f) {
    unsigned u = __float_as_uint(f);
    unsigned r = u + 0x7fffu + ((u >> 16) & 1u);
    return (unsigned short)(r >> 16);
}
__device__ inline float bf2f(unsigned short h) {
    return __uint_as_float((unsigned)h << 16);
}

// ---------------------------------------------------------------------------
// Flatten: (B, D, H, W) -> (B, HW, D) slices, + level embed on src
// ---------------------------------------------------------------------------
__global__ __launch_bounds__(256)
void flatten_k(const float* __restrict__ src, const float* __restrict__ pos,
               const float* __restrict__ lvl, float* __restrict__ src_flat,
               float* __restrict__ pos_flat, int HW, int start)
{
    int hw = blockIdx.x;
    int b  = blockIdx.y;
    int d  = threadIdx.x;
    float sv = src[((size_t)b * 256 + d) * HW + hw];
    float pv = pos[((size_t)b * 256 + d) * HW + hw];
    size_t o = ((size_t)(b * LQ + start + hw)) * 256 + d;
    src_flat[o] = sv + lvl[d];
    pos_flat[o] = pv;
}

// ---------------------------------------------------------------------------
// Weight transpose + bf16 hi/lo split (RNE; runs once): W[L][K][N] -> [L][N][K]
// ---------------------------------------------------------------------------
__global__ __launch_bounds__(256)
void wsplit_k(const float* __restrict__ W, unsigned short* __restrict__ Th,
              unsigned short* __restrict__ Tl, int K, int N,
              long srcStride, long dstStride)
{
    __shared__ float t[32][33];
    int layer = blockIdx.z;
    int n0 = blockIdx.x * 32, k0 = blockIdx.y * 32;
    int tx = threadIdx.x & 31, ty = threadIdx.x >> 5;   // tx: 0..31, ty: 0..7
    const float* Wsrc = W + (size_t)layer * srcStride;
    #pragma unroll
    for (int i = 0; i < 4; ++i)
        t[ty + i * 8][tx] = Wsrc[(size_t)(k0 + ty + i * 8) * N + n0 + tx];
    __syncthreads();
    unsigned short* th = Th + (size_t)layer * dstStride;
    unsigned short* tl = Tl + (size_t)layer * dstStride;
    #pragma unroll
    for (int i = 0; i < 4; ++i) {
        int n = n0 + ty + i * 8;
        float v = t[tx][ty + i * 8];
        unsigned short h = f2bf_rne(v);
        th[(size_t)n * K + k0 + tx] = h;
        tl[(size_t)n * K + k0 + tx] = f2bf_rne(v - bf2f(h));
    }
}

// concat b_off|b_attn -> boa[L][384]
__global__ void boa_k(const float* __restrict__ b_off,
                      const float* __restrict__ b_attn, float* __restrict__ boa)
{
    int l = blockIdx.x, t = threadIdx.x;
    boa[l * 384 + t] = (t < 256) ? b_off[l * 256 + t] : b_attn[l * 128 + (t - 256)];
}

// ---------------------------------------------------------------------------
// bf16x3 split MFMA GEMM: C[M,N] = (A(+A2))[M,K] @ B[K,N] + bias (+Res)(ReLU)
// B pre-transposed/split: Bh/Bl are [N][K] bf16. Tile 128x128x32, 4 waves.
// A split on the fly with TRUNCATION (4 VALU/elem; err ~2^-16 rel).
// ---------------------------------------------------------------------------
template<bool HAS_A2, bool RELU, bool HAS_RES>
__global__ __launch_bounds__(256)
void gemm_mfma(const float* __restrict__ A, const float* __restrict__ A2,
               const unsigned short* __restrict__ Bh,
               const unsigned short* __restrict__ Bl,
               const float* __restrict__ bias, const float* __restrict__ Res,
               float* __restrict__ C, int M, int N, int K)
{
    __shared__ unsigned short sAh[128 * 32];   // [m][k], 64B rows
    __shared__ unsigned short sAl[128 * 32];
    __shared__ unsigned short sBh[128 * 32];   // [n][k]
    __shared__ unsigned short sBl[128 * 32];

    const int tid = threadIdx.x;
    const int m0 = blockIdx.x * 128;
    const int n0 = blockIdx.y * 128;

    const int w  = tid >> 6;           // wave 0..3
    const int l  = tid & 63;
    const int wm = (w >> 1) * 64;      // wave row offset
    const int wn = (w & 1) * 64;       // wave col offset
    const int lr = l & 15;
    const int kb = (l >> 4) * 8;       // k base within 32
    const int rr = (l >> 4) * 4;       // C row base within 16

    const int sm = tid >> 1;           // staging row/col 0..127
    const int sk = (tid & 1) * 16;     // staging k offset (16 elems)
    const int arow = m0 + sm;
    const bool aok = arow < M;

    f32x4 acc[4][4];
    #pragma unroll
    for (int i = 0; i < 4; ++i)
        #pragma unroll
        for (int j = 0; j < 4; ++j)
            acc[i][j] = (f32x4){0.f, 0.f, 0.f, 0.f};

    for (int kt = 0; kt < K; kt += 32) {
        // ---- load A (16 fp32) and B (16+16 bf16) to regs
        float va[16];
        if (aok) {
            const float* ap = &A[(size_t)arow * K + kt + sk];
            *(float4*)&va[0]  = *(const float4*)(ap + 0);
            *(float4*)&va[4]  = *(const float4*)(ap + 4);
            *(float4*)&va[8]  = *(const float4*)(ap + 8);
            *(float4*)&va[12] = *(const float4*)(ap + 12);
            if (HAS_A2) {
                const float* ap2 = &A2[(size_t)arow * K + kt + sk];
                float4 t0 = *(const float4*)(ap2 + 0);
                float4 t1 = *(const float4*)(ap2 + 4);
                float4 t2 = *(const float4*)(ap2 + 8);
                float4 t3 = *(const float4*)(ap2 + 12);
                va[0] += t0.x; va[1] += t0.y; va[2]  += t0.z; va[3]  += t0.w;
                va[4] += t1.x; va[5] += t1.y; va[6]  += t1.z; va[7]  += t1.w;
                va[8] += t2.x; va[9] += t2.y; va[10] += t2.z; va[11] += t2.w;
                va[12]+= t3.x; va[13]+= t3.y; va[14] += t3.z; va[15] += t3.w;
            }
        } else {
            #pragma unroll
            for (int j = 0; j < 16; ++j) va[j] = 0.f;
        }
        const unsigned short* bph = &Bh[(size_t)(n0 + sm) * K + kt + sk];
        const unsigned short* bpl = &Bl[(size_t)(n0 + sm) * K + kt + sk];
        bf16x8 vbh0 = *(const bf16x8*)(bph);
        bf16x8 vbh1 = *(const bf16x8*)(bph + 8);
        bf16x8 vbl0 = *(const bf16x8*)(bpl);
        bf16x8 vbl1 = *(const bf16x8*)(bpl + 8);

        // ---- convert/split A (truncation split)
        bf16x8 ah0, ah1, al0, al1;
        #pragma unroll
        for (int j = 0; j < 8; ++j) {
            float v0 = va[j], v1 = va[8 + j];
            unsigned short h0 = (unsigned short)(__float_as_uint(v0) >> 16);
            unsigned short h1 = (unsigned short)(__float_as_uint(v1) >> 16);
            ah0[j] = (short)h0;
            ah1[j] = (short)h1;
            float r0 = v0 - bf2f(h0);
            float r1 = v1 - bf2f(h1);
            al0[j] = (short)(unsigned short)(__float_as_uint(r0) >> 16);
            al1[j] = (short)(unsigned short)(__float_as_uint(r1) >> 16);
        }

        __syncthreads();   // previous iteration consumers done
        *(bf16x8*)&sAh[sm * 32 + sk]     = ah0;
        *(bf16x8*)&sAh[sm * 32 + sk + 8] = ah1;
        *(bf16x8*)&sAl[sm * 32 + sk]     = al0;
        *(bf16x8*)&sAl[sm * 32 + sk + 8] = al1;
        *(bf16x8*)&sBh[sm * 32 + sk]     = vbh0;
        *(bf16x8*)&sBh[sm * 32 + sk + 8] = vbh1;
        *(bf16x8*)&sBl[sm * 32 + sk]     = vbl0;
        *(bf16x8*)&sBl[sm * 32 + sk + 8] = vbl1;
        __syncthreads();

        // ---- fragments + MFMA
        bf16x8 fah[4], fal[4];
        #pragma unroll
        for (int mf = 0; mf < 4; ++mf) {
            int off = (wm + mf * 16 + lr) * 32 + kb;
            fah[mf] = *(const bf16x8*)&sAh[off];
            fal[mf] = *(const bf16x8*)&sAl[off];
        }
        #pragma unroll
        for (int nf = 0; nf < 4; ++nf) {
            int boff = (wn + nf * 16 + lr) * 32 + kb;
            bf16x8 fbh = *(const bf16x8*)&sBh[boff];
            bf16x8 fbl = *(const bf16x8*)&sBl[boff];
            #pragma unroll
            for (int mf = 0; mf < 4; ++mf) {
                f32x4 c = acc[mf][nf];
                c = __builtin_amdgcn_mfma_f32_16x16x32_bf16(fah[mf], fbh, c, 0, 0, 0);
                c = __builtin_amdgcn_mfma_f32_16x16x32_bf16(fah[mf], fbl, c, 0, 0, 0);
                c = __builtin_amdgcn_mfma_f32_16x16x32_bf16(fal[mf], fbh, c, 0, 0, 0);
                acc[mf][nf] = c;
            }
        }
    }

    // ---- epilogue
    #pragma unroll
    for (int nf = 0; nf < 4; ++nf) {
        int col = n0 + wn + nf * 16 + lr;
        float bs = bias[col];
        #pragma unroll
        for (int mf = 0; mf < 4; ++mf) {
            int rowb = m0 + wm + mf * 16 + rr;
            #pragma unroll
            for (int r = 0; r < 4; ++r) {
                int row = rowb + r;
                if (row < M) {
                    float v = acc[mf][nf][r] + bs;
                    if (HAS_RES) v += Res[(size_t)row * N + col];
                    if (RELU) v = fmaxf(v, 0.f);
                    C[(size_t)row * N + col] = v;
                }
            }
        }
    }
}

// ---------------------------------------------------------------------------
// Deformable sampling. Block = (q,b), XCD-swizzled q for L2 locality.
// Phase A (128 thr): softmax + fused corner (idx,weight) -> LDS.
// Phase B: 4 waves; wave covers 2 heads; lane = (head-half, corner, ch-quad);
// float4 gathers (1KB/wave-instr), branchless, shfl corner-reduction.
// ---------------------------------------------------------------------------
__global__ __launch_bounds__(256)
void sample_k(const float* __restrict__ val, const float* __restrict__ oab,
              float* __restrict__ out)
{
    const int Hs[4] = {76, 38, 19, 10};
    const int Ws[4] = {100, 50, 25, 13};
    const int ST[4] = {0, 7600, 9500, 9975};

    // bijective XCD chunk swizzle (LQ % 8 == 1): xcd 0 gets 1264 q's, others 1263
    int bid = blockIdx.x;
    int xcd = bid & 7;
    const int qch = LQ >> 3;            // 1263
    const int rem = LQ & 7;             // 1
    int q = (xcd < rem ? xcd * (qch + 1) : rem * (qch + 1) + (xcd - rem) * qch)
            + (bid >> 3);
    int b = blockIdx.y;
    int tid = threadIdx.x;

    __shared__ int2 s_iw[512];   // (idx, weight-bits) per (h,pt,corner)

    if (tid < 128) {
        int h = tid >> 4, pt = tid & 15, lvl = pt >> 2, p = pt & 3;
        int lq, local;
        if (q < 7600)      { lq = 0; local = q; }
        else if (q < 9500) { lq = 1; local = q - 7600; }
        else if (q < 9975) { lq = 2; local = q - 9500; }
        else               { lq = 3; local = q - 9975; }
        int Wq = Ws[lq], Hq = Hs[lq];
        int ry = local / Wq, rx = local - ry * Wq;
        float refx = (rx + 0.5f) / (float)Wq;
        float refy = (ry + 0.5f) / (float)Hq;

        size_t rowb = (size_t)(b * LQ + q) * 384;
        float logit = oab[rowb + 256 + h * 16 + pt];
        float mx = logit;
        mx = fmaxf(mx, __shfl_xor(mx, 1, 64));
        mx = fmaxf(mx, __shfl_xor(mx, 2, 64));
        mx = fmaxf(mx, __shfl_xor(mx, 4, 64));
        mx = fmaxf(mx, __shfl_xor(mx, 8, 64));
        float e = expf(logit - mx);
        float s = e;
        s += __shfl_xor(s, 1, 64);
        s += __shfl_xor(s, 2, 64);
        s += __shfl_xor(s, 4, 64);
        s += __shfl_xor(s, 8, 64);
        float aw = e / s;

        float ox = oab[rowb + h * 32 + lvl * 8 + p * 2];
        float oy = oab[rowb + h * 32 + lvl * 8 + p * 2 + 1];
        int W = Ws[lvl], H = Hs[lvl], st = ST[lvl];
        float px = refx * (float)W + ox - 0.5f;
        float py = refy * (float)H + oy - 0.5f;
        float x0f = floorf(px), y0f = floorf(py);
        float lx = px - x0f, ly = py - y0f;
        int x0 = (int)x0f, y0 = (int)y0f;
        int x1 = x0 + 1, y1 = y0 + 1;
        float ax0 = ((x0 >= 0) & (x0 < W)) ? (1.f - lx) : 0.f;
        float ax1 = ((x1 >= 0) & (x1 < W)) ? lx : 0.f;
        float ay0 = ((y0 >= 0) & (y0 < H)) ? (1.f - ly) : 0.f;
        float ay1 = ((y1 >= 0) & (y1 < H)) ? ly : 0.f;
        int cx0 = min(max(x0, 0), W - 1), cx1 = min(max(x1, 0), W - 1);
        int cy0 = min(max(y0, 0), H - 1), cy1 = min(max(y1, 0), H - 1);
        int i00 = st + cy0 * W + cx0, i01 = st + cy0 * W + cx1;
        int i10 = st + cy1 * W + cx0, i11 = st + cy1 * W + cx1;
        int base4 = tid * 4;
        s_iw[base4 + 0] = make_int2(i00, __float_as_int(aw * ay0 * ax0));
        s_iw[base4 + 1] = make_int2(i01, __float_as_int(aw * ay0 * ax1));
        s_iw[base4 + 2] = make_int2(i10, __float_as_int(aw * ay1 * ax0));
        s_iw[base4 + 3] = make_int2(i11, __float_as_int(aw * ay1 * ax1));
    }
    __syncthreads();

    int lane   = tid & 63;
    int wv     = tid >> 6;
    int h      = wv * 2 + (lane >> 5);   // head 0..7
    int half   = lane & 31;
    int corner = half >> 3;              // 0..3
    int c4     = half & 7;               // channel quad 0..7
    const float* vb = val + (size_t)(b * LQ) * 256 + h * 32 + c4 * 4;
    int sbase = h * 64 + corner;

    float4 acc = make_float4(0.f, 0.f, 0.f, 0.f);
    #pragma unroll
    for (int pt = 0; pt < 16; ++pt) {
        int2 iw = s_iw[sbase + pt * 4];
        float wgt = __int_as_float(iw.y);
        float4 v = *(const float4*)&vb[(size_t)iw.x * 256];
        acc.x += wgt * v.x; acc.y += wgt * v.y;
        acc.z += wgt * v.z; acc.w += wgt * v.w;
    }
    // reduce across the 4 corner groups (lane bits 3,4)
    acc.x += __shfl_xor(acc.x, 8, 64);  acc.y += __shfl_xor(acc.y, 8, 64);
    acc.z += __shfl_xor(acc.z, 8, 64);  acc.w += __shfl_xor(acc.w, 8, 64);
    acc.x += __shfl_xor(acc.x, 16, 64); acc.y += __shfl_xor(acc.y, 16, 64);
    acc.z += __shfl_xor(acc.z, 16, 64); acc.w += __shfl_xor(acc.w, 16, 64);

    if (corner == 0)
        *(float4*)&out[(size_t)(b * LQ + q) * 256 + h * 32 + c4 * 4] = acc;
}

// ---------------------------------------------------------------------------
// LayerNorm over D=256: 4 rows/block, one wave per row, float4/lane, no LDS
// ---------------------------------------------------------------------------
__global__ __launch_bounds__(256)
void ln_k(const float* __restrict__ x, const float* __restrict__ g,
          const float* __restrict__ bt, float* __restrict__ out, int nrows)
{
    int row = blockIdx.x * 4 + (threadIdx.x >> 6);
    int lane = threadIdx.x & 63;
    if (row >= nrows) return;

    float4 v = *(const float4*)&x[(size_t)row * 256 + lane * 4];
    float s = v.x + v.y + v.z + v.w;
    #pragma unroll
    for (int o = 32; o > 0; o >>= 1) s += __shfl_down(s, o, 64);
    s = __shfl(s, 0, 64);
    float m = s * (1.0f / 256.0f);
    float cx = v.x - m, cy = v.y - m, cz = v.z - m, cw = v.w - m;
    float s2 = cx * cx + cy * cy + cz * cz + cw * cw;
    #pragma unroll
    for (int o = 32; o > 0; o >>= 1) s2 += __shfl_down(s2, o, 64);
    s2 = __shfl(s2, 0, 64);
    float rstd = rsqrtf(s2 * (1.0f / 256.0f) + 1e-5f);

    float4 gv = *(const float4*)&g[lane * 4];
    float4 bv = *(const float4*)&bt[lane * 4];
    float4 r;
    r.x = cx * rstd * gv.x + bv.x;
    r.y = cy * rstd * gv.y + bv.y;
    r.z = cz * rstd * gv.z + bv.z;
    r.w = cw * rstd * gv.w + bv.w;
    *(float4*)&out[(size_t)row * 256 + lane * 4] = r;
}

// ---------------------------------------------------------------------------
extern "C" void kernel_launch(void* const* d_in, const int* in_sizes, int n_in,
                              void* d_out, int out_size, void* d_ws, size_t ws_size,
                              hipStream_t stream)
{
    const float* src_in[4] = {(const float*)d_in[0], (const float*)d_in[2],
                              (const float*)d_in[4], (const float*)d_in[6]};
    const float* pos_in[4] = {(const float*)d_in[1], (const float*)d_in[3],
                              (const float*)d_in[5], (const float*)d_in[7]};
    const float* lvl    = (const float*)d_in[8];
    const float* w_off  = (const float*)d_in[9];
    const float* b_off  = (const float*)d_in[10];
    const float* w_attn = (const float*)d_in[11];
    const float* b_attn = (const float*)d_in[12];
    const float* w_val  = (const float*)d_in[13];
    const float* b_val  = (const float*)d_in[14];
    const float* w_out  = (const float*)d_in[15];
    const float* b_out  = (const float*)d_in[16];
    const float* ln1_g  = (const float*)d_in[17];
    const float* ln1_b  = (const float*)d_in[18];
    const float* w_ffn1 = (const float*)d_in[19];
    const float* b_ffn1 = (const float*)d_in[20];
    const float* w_ffn2 = (const float*)d_in[21];
    const float* b_ffn2 = (const float*)d_in[22];
    const float* ln2_g  = (const float*)d_in[23];
    const float* ln2_b  = (const float*)d_in[24];

    // ---- workspace layout (floats then bf16 weight area) ----
    float* ws    = (float*)d_ws;
    float* src   = ws;                              // NTOK*256
    float* pos   = src   + (size_t)NTOK * 256;      // NTOK*256
    float* preln = pos   + (size_t)NTOK * 256;      // NTOK*256
    float* uni   = preln + (size_t)NTOK * 256;      // NTOK*1024 union region
    float* valb  = uni;                             // NTOK*256   (phase 1)
    float* oab   = uni + (size_t)NTOK * 256;        // NTOK*384   (phase 1)
    float* samp  = oab + (size_t)NTOK * 384;        // NTOK*256   (phase 1)
    float* ffnb  = uni;                             // NTOK*1024  (phase 2)
    float* boa   = uni + (size_t)NTOK * 1024;       // 6*384
    unsigned short* Wh = (unsigned short*)(boa + 6 * 384);
    const long WL = 753664;                         // per-layer bf16 elems
    unsigned short* Wl = Wh + (size_t)NLAYERS * WL;
    const long O_VAL = 0, O_OFF = 65536, O_ATT = 131072, O_OUT = 163840,
               O_F1 = 229376, O_F2 = 491520;

    // ---- weight prep (every call; static content) ----
    wsplit_k<<<dim3(8, 8, 6),  256, 0, stream>>>(w_val,  Wh + O_VAL, Wl + O_VAL, 256, 256,  65536, WL);
    wsplit_k<<<dim3(8, 8, 6),  256, 0, stream>>>(w_off,  Wh + O_OFF, Wl + O_OFF, 256, 256,  65536, WL);
    wsplit_k<<<dim3(4, 8, 6),  256, 0, stream>>>(w_attn, Wh + O_ATT, Wl + O_ATT, 256, 128,  32768, WL);
    wsplit_k<<<dim3(8, 8, 6),  256, 0, stream>>>(w_out,  Wh + O_OUT, Wl + O_OUT, 256, 256,  65536, WL);
    wsplit_k<<<dim3(32, 8, 6), 256, 0, stream>>>(w_ffn1, Wh + O_F1,  Wl + O_F1,  256, 1024, 262144, WL);
    wsplit_k<<<dim3(8, 32, 6), 256, 0, stream>>>(w_ffn2, Wh + O_F2,  Wl + O_F2,  1024, 256, 262144, WL);
    boa_k<<<dim3(6), dim3(384), 0, stream>>>(b_off, b_attn, boa);

    const int HWs[4] = {7600, 1900, 475, 130};
    const int STt[4] = {0, 7600, 9500, 9975};
    for (int l = 0; l < 4; ++l) {
        dim3 g(HWs[l], BATCH);
        flatten_k<<<g, 256, 0, stream>>>(src_in[l], pos_in[l], lvl + l * 256,
                                         src, pos, HWs[l], STt[l]);
    }

    const int MB = (NTOK + 127) / 128;   // 158
    const int LNB = (NTOK + 3) / 4;      // 5053
    dim3 blk(256);

    for (int i = 0; i < NLAYERS; ++i) {
        const unsigned short* whL = Wh + (size_t)i * WL;
        const unsigned short* wlL = Wl + (size_t)i * WL;
        const float* bv  = b_val  + (size_t)i * 256;
        const float* bou = b_out  + (size_t)i * 256;
        const float* l1g = ln1_g  + (size_t)i * 256;
        const float* l1b = ln1_b  + (size_t)i * 256;
        const float* bf1 = b_ffn1 + (size_t)i * 1024;
        const float* bf2 = b_ffn2 + (size_t)i * 256;
        const float* l2g = ln2_g  + (size_t)i * 256;
        const float* l2b = ln2_b  + (size_t)i * 256;

        // value = src @ w_val + b_val
        gemm_mfma<false, false, false><<<dim3(MB, 2), blk, 0, stream>>>(
            src, nullptr, whL + O_VAL, wlL + O_VAL, bv, nullptr, valb, NTOK, 256, 256);
        // [off|attn] = (src+pos) @ [w_off|w_attn] + [b_off|b_attn]   (N=384 fused)
        gemm_mfma<true, false, false><<<dim3(MB, 3), blk, 0, stream>>>(
            src, pos, whL + O_OFF, wlL + O_OFF, boa + (size_t)i * 384, nullptr,
            oab, NTOK, 384, 256);
        // deformable sampling -> samp
        sample_k<<<dim3(LQ, BATCH), blk, 0, stream>>>(valb, oab, samp);
        // attn_out = samp @ w_out + b_out + src -> preln
        gemm_mfma<false, false, true><<<dim3(MB, 2), blk, 0, stream>>>(
            samp, nullptr, whL + O_OUT, wlL + O_OUT, bou, src, preln, NTOK, 256, 256);
        // LN1 -> src
        ln_k<<<dim3(LNB), blk, 0, stream>>>(preln, l1g, l1b, src, NTOK);
        // ffn1 = relu(src @ w_ffn1 + b_ffn1) -> ffnb
        gemm_mfma<false, true, false><<<dim3(MB, 8), blk, 0, stream>>>(
            src, nullptr, whL + O_F1, wlL + O_F1, bf1, nullptr, ffnb, NTOK, 1024, 256);
        // ffn2 = ffnb @ w_ffn2 + b_ffn2 + src -> preln
        gemm_mfma<false, false, true><<<dim3(MB, 2), blk, 0, stream>>>(
            ffnb, nullptr, whL + O_F2, wlL + O_F2, bf2, src, preln, NTOK, 256, 1024);
        // LN2 -> src (or d_out on last layer)
        float* dst = (i == NLAYERS - 1) ? (float*)d_out : src;
        ln_k<<<dim3(LNB), blk, 0, stream>>>(preln, l2g, l2b, dst, NTOK);
    }
}

// Round 5
// 1755.956 us; speedup vs baseline: 2.5504x; 1.0946x over previous
//
#include <hip/hip_runtime.h>
#include <math.h>

#define LQ 10105
#define BATCH 2
#define NLAYERS 6
#define NTOK (BATCH * LQ)   // 20210

typedef __attribute__((ext_vector_type(8))) short bf16x8;   // 8 bf16 (4 VGPRs)
typedef __attribute__((ext_vector_type(4))) float f32x4;

__device__ inline unsigned short f2bf_rne(float f) {
    unsigned u = __float_as_uint(f);
    unsigned r = u + 0x7fffu + ((u >> 16) & 1u);
    return (unsigned short)(r >> 16);
}
__device__ inline float bf2f(unsigned short h) {
    return __uint_as_float((unsigned)h << 16);
}

// ---------------------------------------------------------------------------
// Flatten: (B, D, H, W) -> (B, HW, D) slices, + level embed on src
// ---------------------------------------------------------------------------
__global__ __launch_bounds__(256)
void flatten_k(const float* __restrict__ src, const float* __restrict__ pos,
               const float* __restrict__ lvl, float* __restrict__ src_flat,
               float* __restrict__ pos_flat, int HW, int start)
{
    int hw = blockIdx.x;
    int b  = blockIdx.y;
    int d  = threadIdx.x;
    float sv = src[((size_t)b * 256 + d) * HW + hw];
    float pv = pos[((size_t)b * 256 + d) * HW + hw];
    size_t o = ((size_t)(b * LQ + start + hw)) * 256 + d;
    src_flat[o] = sv + lvl[d];
    pos_flat[o] = pv;
}

// ---------------------------------------------------------------------------
// Weight transpose + bf16 hi/lo split: W[L][K][N] fp32 -> Th/Tl[L][N][K] bf16
// ---------------------------------------------------------------------------
__global__ __launch_bounds__(256)
void wsplit_k(const float* __restrict__ W, unsigned short* __restrict__ Th,
              unsigned short* __restrict__ Tl, int K, int N,
              long srcStride, long dstStride)
{
    __shared__ float t[32][33];
    int layer = blockIdx.z;
    int n0 = blockIdx.x * 32, k0 = blockIdx.y * 32;
    int tx = threadIdx.x & 31, ty = threadIdx.x >> 5;   // tx: 0..31, ty: 0..7
    const float* Wsrc = W + (size_t)layer * srcStride;
    #pragma unroll
    for (int i = 0; i < 4; ++i)
        t[ty + i * 8][tx] = Wsrc[(size_t)(k0 + ty + i * 8) * N + n0 + tx];
    __syncthreads();
    unsigned short* th = Th + (size_t)layer * dstStride;
    unsigned short* tl = Tl + (size_t)layer * dstStride;
    #pragma unroll
    for (int i = 0; i < 4; ++i) {
        int n = n0 + ty + i * 8;
        float v = t[tx][ty + i * 8];
        unsigned short h = f2bf_rne(v);
        th[(size_t)n * K + k0 + tx] = h;
        tl[(size_t)n * K + k0 + tx] = f2bf_rne(v - bf2f(h));
    }
}

// concat b_off|b_attn -> boa[L][384]
__global__ void boa_k(const float* __restrict__ b_off,
                      const float* __restrict__ b_attn, float* __restrict__ boa)
{
    int l = blockIdx.x, t = threadIdx.x;
    boa[l * 384 + t] = (t < 256) ? b_off[l * 256 + t] : b_attn[l * 128 + (t - 256)];
}

// ---------------------------------------------------------------------------
// bf16-split MFMA GEMM. Tile 128x128x32, 4 waves, LDS rows padded to 40 bf16
// (80 B) -> fragment ds_read_b128 is 2-way (free) instead of 8-way conflict.
// 1-D grid, m-major work order + bijective XCD chunk swizzle for A L2-reuse.
// A fp32 (split 3-pass) or bf16 (exact, 2-pass). C fp32 or bf16.
// ---------------------------------------------------------------------------
template<bool A_BF16, bool HAS_A2, bool RELU, bool HAS_RES, bool C_BF16>
__global__ __launch_bounds__(256)
void gemm_mfma(const void* __restrict__ Av, const float* __restrict__ A2,
               const unsigned short* __restrict__ Bh,
               const unsigned short* __restrict__ Bl,
               const float* __restrict__ bias, const float* __restrict__ Res,
               void* __restrict__ Cv, int M, int N, int K, int NB)
{
    constexpr int LDR = 40;                     // padded LDS row stride (bf16)
    constexpr int PLANES = A_BF16 ? 3 : 4;
    __shared__ unsigned short sMem[PLANES * 128 * LDR];
    unsigned short* sBh = sMem;
    unsigned short* sBl = sMem + 128 * LDR;
    unsigned short* sAh = sMem + 2 * 128 * LDR;
    unsigned short* sAl = sMem + (PLANES - 1) * 128 * LDR;  // last plane (fp32 path)

    // ---- bijective XCD chunk swizzle; within chunk: m-major over n-blocks
    const int nwg = gridDim.x;
    const int bid = blockIdx.x;
    const int q8 = nwg >> 3, r8 = nwg & 7, xcd = bid & 7;
    const int work = (xcd < r8 ? xcd * (q8 + 1) : r8 * (q8 + 1) + (xcd - r8) * q8)
                     + (bid >> 3);
    const int mblk = work / NB;
    const int m0 = mblk * 128;
    const int n0 = (work - mblk * NB) * 128;

    const int tid = threadIdx.x;
    const int w  = tid >> 6;           // wave 0..3
    const int l  = tid & 63;
    const int wm = (w >> 1) * 64;      // wave row offset
    const int wn = (w & 1) * 64;       // wave col offset
    const int lr = l & 15;
    const int kb = (l >> 4) * 8;       // k base within 32
    const int rr = (l >> 4) * 4;       // C row base within 16

    const int sm = tid >> 1;           // staging row/col 0..127
    const int sk = (tid & 1) * 16;     // staging k offset (16 elems)
    const int arow = m0 + sm;
    const bool aok = arow < M;

    f32x4 acc[4][4];
    #pragma unroll
    for (int i = 0; i < 4; ++i)
        #pragma unroll
        for (int j = 0; j < 4; ++j)
            acc[i][j] = (f32x4){0.f, 0.f, 0.f, 0.f};

    for (int kt = 0; kt < K; kt += 32) {
        // ---- B tile to regs
        const unsigned short* bph = &Bh[(size_t)(n0 + sm) * K + kt + sk];
        const unsigned short* bpl = &Bl[(size_t)(n0 + sm) * K + kt + sk];
        bf16x8 vbh0 = *(const bf16x8*)(bph);
        bf16x8 vbh1 = *(const bf16x8*)(bph + 8);
        bf16x8 vbl0 = *(const bf16x8*)(bpl);
        bf16x8 vbl1 = *(const bf16x8*)(bpl + 8);

        bf16x8 ah0 = {}, ah1 = {}, al0 = {}, al1 = {};
        if constexpr (A_BF16) {
            if (aok) {
                const unsigned short* ap =
                    (const unsigned short*)Av + (size_t)arow * K + kt + sk;
                ah0 = *(const bf16x8*)ap;
                ah1 = *(const bf16x8*)(ap + 8);
            }
        } else {
            float va[16];
            if (aok) {
                const float* ap = (const float*)Av + (size_t)arow * K + kt + sk;
                *(float4*)&va[0]  = *(const float4*)(ap + 0);
                *(float4*)&va[4]  = *(const float4*)(ap + 4);
                *(float4*)&va[8]  = *(const float4*)(ap + 8);
                *(float4*)&va[12] = *(const float4*)(ap + 12);
                if (HAS_A2) {
                    const float* ap2 = &A2[(size_t)arow * K + kt + sk];
                    float4 t0 = *(const float4*)(ap2 + 0);
                    float4 t1 = *(const float4*)(ap2 + 4);
                    float4 t2 = *(const float4*)(ap2 + 8);
                    float4 t3 = *(const float4*)(ap2 + 12);
                    va[0] += t0.x; va[1] += t0.y; va[2]  += t0.z; va[3]  += t0.w;
                    va[4] += t1.x; va[5] += t1.y; va[6]  += t1.z; va[7]  += t1.w;
                    va[8] += t2.x; va[9] += t2.y; va[10] += t2.z; va[11] += t2.w;
                    va[12]+= t3.x; va[13]+= t3.y; va[14] += t3.z; va[15] += t3.w;
                }
            } else {
                #pragma unroll
                for (int j = 0; j < 16; ++j) va[j] = 0.f;
            }
            #pragma unroll
            for (int j = 0; j < 8; ++j) {
                float v0 = va[j], v1 = va[8 + j];
                unsigned short h0 = (unsigned short)(__float_as_uint(v0) >> 16);
                unsigned short h1 = (unsigned short)(__float_as_uint(v1) >> 16);
                ah0[j] = (short)h0;
                ah1[j] = (short)h1;
                float r0 = v0 - bf2f(h0);
                float r1 = v1 - bf2f(h1);
                al0[j] = (short)(unsigned short)(__float_as_uint(r0) >> 16);
                al1[j] = (short)(unsigned short)(__float_as_uint(r1) >> 16);
            }
        }

        __syncthreads();   // previous iteration consumers done
        *(bf16x8*)&sAh[sm * LDR + sk]     = ah0;
        *(bf16x8*)&sAh[sm * LDR + sk + 8] = ah1;
        if constexpr (!A_BF16) {
            *(bf16x8*)&sAl[sm * LDR + sk]     = al0;
            *(bf16x8*)&sAl[sm * LDR + sk + 8] = al1;
        }
        *(bf16x8*)&sBh[sm * LDR + sk]     = vbh0;
        *(bf16x8*)&sBh[sm * LDR + sk + 8] = vbh1;
        *(bf16x8*)&sBl[sm * LDR + sk]     = vbl0;
        *(bf16x8*)&sBl[sm * LDR + sk + 8] = vbl1;
        __syncthreads();

        // ---- fragments + MFMA
        bf16x8 fah[4], fal[4];
        #pragma unroll
        for (int mf = 0; mf < 4; ++mf) {
            int off = (wm + mf * 16 + lr) * LDR + kb;
            fah[mf] = *(const bf16x8*)&sAh[off];
            if constexpr (!A_BF16) fal[mf] = *(const bf16x8*)&sAl[off];
        }
        #pragma unroll
        for (int nf = 0; nf < 4; ++nf) {
            int boff = (wn + nf * 16 + lr) * LDR + kb;
            bf16x8 fbh = *(const bf16x8*)&sBh[boff];
            bf16x8 fbl = *(const bf16x8*)&sBl[boff];
            #pragma unroll
            for (int mf = 0; mf < 4; ++mf) {
                f32x4 c = acc[mf][nf];
                c = __builtin_amdgcn_mfma_f32_16x16x32_bf16(fah[mf], fbh, c, 0, 0, 0);
                c = __builtin_amdgcn_mfma_f32_16x16x32_bf16(fah[mf], fbl, c, 0, 0, 0);
                if constexpr (!A_BF16)
                    c = __builtin_amdgcn_mfma_f32_16x16x32_bf16(fal[mf], fbh, c, 0, 0, 0);
                acc[mf][nf] = c;
            }
        }
    }

    // ---- epilogue
    float* Cf = (float*)Cv;
    unsigned short* Cb = (unsigned short*)Cv;
    #pragma unroll
    for (int nf = 0; nf < 4; ++nf) {
        int col = n0 + wn + nf * 16 + lr;
        float bs = bias[col];
        #pragma unroll
        for (int mf = 0; mf < 4; ++mf) {
            int rowb = m0 + wm + mf * 16 + rr;
            #pragma unroll
            for (int r = 0; r < 4; ++r) {
                int row = rowb + r;
                if (row < M) {
                    float v = acc[mf][nf][r] + bs;
                    if (HAS_RES) v += Res[(size_t)row * N + col];
                    if (RELU) v = fmaxf(v, 0.f);
                    if constexpr (C_BF16)
                        Cb[(size_t)row * N + col] = f2bf_rne(v);
                    else
                        Cf[(size_t)row * N + col] = v;
                }
            }
        }
    }
}

// ---------------------------------------------------------------------------
// Deformable sampling. Block = (q,b), XCD-swizzled q. val/out in bf16.
// Phase A (128 thr): softmax + fused corner (idx,weight) -> LDS.
// Phase B: lane = (head-half, corner, ch-quad); ushort4 gathers, branchless,
// shfl corner-reduction.
// ---------------------------------------------------------------------------
__global__ __launch_bounds__(256)
void sample_k(const unsigned short* __restrict__ val,
              const float* __restrict__ oab, unsigned short* __restrict__ out)
{
    const int Hs[4] = {76, 38, 19, 10};
    const int Ws[4] = {100, 50, 25, 13};
    const int ST[4] = {0, 7600, 9500, 9975};

    int bid = blockIdx.x;
    int xcd = bid & 7;
    const int qch = LQ >> 3;
    const int rem = LQ & 7;
    int q = (xcd < rem ? xcd * (qch + 1) : rem * (qch + 1) + (xcd - rem) * qch)
            + (bid >> 3);
    int b = blockIdx.y;
    int tid = threadIdx.x;

    __shared__ int2 s_iw[512];

    if (tid < 128) {
        int h = tid >> 4, pt = tid & 15, lvl = pt >> 2, p = pt & 3;
        int lq, local;
        if (q < 7600)      { lq = 0; local = q; }
        else if (q < 9500) { lq = 1; local = q - 7600; }
        else if (q < 9975) { lq = 2; local = q - 9500; }
        else               { lq = 3; local = q - 9975; }
        int Wq = Ws[lq], Hq = Hs[lq];
        int ry = local / Wq, rx = local - ry * Wq;
        float refx = (rx + 0.5f) / (float)Wq;
        float refy = (ry + 0.5f) / (float)Hq;

        size_t rowb = (size_t)(b * LQ + q) * 384;
        float logit = oab[rowb + 256 + h * 16 + pt];
        float mx = logit;
        mx = fmaxf(mx, __shfl_xor(mx, 1, 64));
        mx = fmaxf(mx, __shfl_xor(mx, 2, 64));
        mx = fmaxf(mx, __shfl_xor(mx, 4, 64));
        mx = fmaxf(mx, __shfl_xor(mx, 8, 64));
        float e = expf(logit - mx);
        float s = e;
        s += __shfl_xor(s, 1, 64);
        s += __shfl_xor(s, 2, 64);
        s += __shfl_xor(s, 4, 64);
        s += __shfl_xor(s, 8, 64);
        float aw = e / s;

        float ox = oab[rowb + h * 32 + lvl * 8 + p * 2];
        float oy = oab[rowb + h * 32 + lvl * 8 + p * 2 + 1];
        int W = Ws[lvl], H = Hs[lvl], st = ST[lvl];
        float px = refx * (float)W + ox - 0.5f;
        float py = refy * (float)H + oy - 0.5f;
        float x0f = floorf(px), y0f = floorf(py);
        float lx = px - x0f, ly = py - y0f;
        int x0 = (int)x0f, y0 = (int)y0f;
        int x1 = x0 + 1, y1 = y0 + 1;
        float ax0 = ((x0 >= 0) & (x0 < W)) ? (1.f - lx) : 0.f;
        float ax1 = ((x1 >= 0) & (x1 < W)) ? lx : 0.f;
        float ay0 = ((y0 >= 0) & (y0 < H)) ? (1.f - ly) : 0.f;
        float ay1 = ((y1 >= 0) & (y1 < H)) ? ly : 0.f;
        int cx0 = min(max(x0, 0), W - 1), cx1 = min(max(x1, 0), W - 1);
        int cy0 = min(max(y0, 0), H - 1), cy1 = min(max(y1, 0), H - 1);
        int i00 = st + cy0 * W + cx0, i01 = st + cy0 * W + cx1;
        int i10 = st + cy1 * W + cx0, i11 = st + cy1 * W + cx1;
        int base4 = tid * 4;
        s_iw[base4 + 0] = make_int2(i00, __float_as_int(aw * ay0 * ax0));
        s_iw[base4 + 1] = make_int2(i01, __float_as_int(aw * ay0 * ax1));
        s_iw[base4 + 2] = make_int2(i10, __float_as_int(aw * ay1 * ax0));
        s_iw[base4 + 3] = make_int2(i11, __float_as_int(aw * ay1 * ax1));
    }
    __syncthreads();

    int lane   = tid & 63;
    int wv     = tid >> 6;
    int h      = wv * 2 + (lane >> 5);   // head 0..7
    int half   = lane & 31;
    int corner = half >> 3;              // 0..3
    int c4     = half & 7;               // channel quad 0..7
    const unsigned short* vb = val + (size_t)(b * LQ) * 256 + h * 32 + c4 * 4;
    int sbase = h * 64 + corner;

    float4 acc = make_float4(0.f, 0.f, 0.f, 0.f);
    #pragma unroll
    for (int pt = 0; pt < 16; ++pt) {
        int2 iw = s_iw[sbase + pt * 4];
        float wgt = __int_as_float(iw.y);
        ushort4 v = *(const ushort4*)&vb[(size_t)iw.x * 256];
        acc.x += wgt * bf2f(v.x); acc.y += wgt * bf2f(v.y);
        acc.z += wgt * bf2f(v.z); acc.w += wgt * bf2f(v.w);
    }
    acc.x += __shfl_xor(acc.x, 8, 64);  acc.y += __shfl_xor(acc.y, 8, 64);
    acc.z += __shfl_xor(acc.z, 8, 64);  acc.w += __shfl_xor(acc.w, 8, 64);
    acc.x += __shfl_xor(acc.x, 16, 64); acc.y += __shfl_xor(acc.y, 16, 64);
    acc.z += __shfl_xor(acc.z, 16, 64); acc.w += __shfl_xor(acc.w, 16, 64);

    if (corner == 0) {
        ushort4 o;
        o.x = f2bf_rne(acc.x); o.y = f2bf_rne(acc.y);
        o.z = f2bf_rne(acc.z); o.w = f2bf_rne(acc.w);
        *(ushort4*)&out[(size_t)(b * LQ + q) * 256 + h * 32 + c4 * 4] = o;
    }
}

// ---------------------------------------------------------------------------
// LayerNorm over D=256: 4 rows/block, one wave per row, float4/lane, no LDS
// ---------------------------------------------------------------------------
__global__ __launch_bounds__(256)
void ln_k(const float* __restrict__ x, const float* __restrict__ g,
          const float* __restrict__ bt, float* __restrict__ out, int nrows)
{
    int row = blockIdx.x * 4 + (threadIdx.x >> 6);
    int lane = threadIdx.x & 63;
    if (row >= nrows) return;

    float4 v = *(const float4*)&x[(size_t)row * 256 + lane * 4];
    float s = v.x + v.y + v.z + v.w;
    #pragma unroll
    for (int o = 32; o > 0; o >>= 1) s += __shfl_down(s, o, 64);
    s = __shfl(s, 0, 64);
    float m = s * (1.0f / 256.0f);
    float cx = v.x - m, cy = v.y - m, cz = v.z - m, cw = v.w - m;
    float s2 = cx * cx + cy * cy + cz * cz + cw * cw;
    #pragma unroll
    for (int o = 32; o > 0; o >>= 1) s2 += __shfl_down(s2, o, 64);
    s2 = __shfl(s2, 0, 64);
    float rstd = rsqrtf(s2 * (1.0f / 256.0f) + 1e-5f);

    float4 gv = *(const float4*)&g[lane * 4];
    float4 bv = *(const float4*)&bt[lane * 4];
    float4 r;
    r.x = cx * rstd * gv.x + bv.x;
    r.y = cy * rstd * gv.y + bv.y;
    r.z = cz * rstd * gv.z + bv.z;
    r.w = cw * rstd * gv.w + bv.w;
    *(float4*)&out[(size_t)row * 256 + lane * 4] = r;
}

// ---------------------------------------------------------------------------
extern "C" void kernel_launch(void* const* d_in, const int* in_sizes, int n_in,
                              void* d_out, int out_size, void* d_ws, size_t ws_size,
                              hipStream_t stream)
{
    const float* src_in[4] = {(const float*)d_in[0], (const float*)d_in[2],
                              (const float*)d_in[4], (const float*)d_in[6]};
    const float* pos_in[4] = {(const float*)d_in[1], (const float*)d_in[3],
                              (const float*)d_in[5], (const float*)d_in[7]};
    const float* lvl    = (const float*)d_in[8];
    const float* w_off  = (const float*)d_in[9];
    const float* b_off  = (const float*)d_in[10];
    const float* w_attn = (const float*)d_in[11];
    const float* b_attn = (const float*)d_in[12];
    const float* w_val  = (const float*)d_in[13];
    const float* b_val  = (const float*)d_in[14];
    const float* w_out  = (const float*)d_in[15];
    const float* b_out  = (const float*)d_in[16];
    const float* ln1_g  = (const float*)d_in[17];
    const float* ln1_b  = (const float*)d_in[18];
    const float* w_ffn1 = (const float*)d_in[19];
    const float* b_ffn1 = (const float*)d_in[20];
    const float* w_ffn2 = (const float*)d_in[21];
    const float* b_ffn2 = (const float*)d_in[22];
    const float* ln2_g  = (const float*)d_in[23];
    const float* ln2_b  = (const float*)d_in[24];

    // ---- workspace layout ----
    float* ws    = (float*)d_ws;
    float* src   = ws;                              // NTOK*256 f32
    float* pos   = src   + (size_t)NTOK * 256;      // NTOK*256 f32
    float* preln = pos   + (size_t)NTOK * 256;      // NTOK*256 f32
    char*  uni   = (char*)(preln + (size_t)NTOK * 256);
    // phase-1 union: valb bf16 | oab f32 | samp bf16 ; phase-2: ffnb bf16
    unsigned short* valb = (unsigned short*)uni;                      // NTOK*256 u16
    float* oab = (float*)(uni + (size_t)NTOK * 512);                  // NTOK*384 f32
    unsigned short* samp = (unsigned short*)(uni + (size_t)NTOK * 2048); // NTOK*256 u16
    unsigned short* ffnb = (unsigned short*)uni;                      // NTOK*1024 u16
    float* boa = (float*)(uni + (size_t)NTOK * 2560);                 // 6*384
    unsigned short* Wh = (unsigned short*)(boa + 6 * 384);
    const long WL = 753664;                         // per-layer bf16 elems
    unsigned short* Wl = Wh + (size_t)NLAYERS * WL;
    const long O_VAL = 0, O_OFF = 65536, O_ATT = 131072, O_OUT = 163840,
               O_F1 = 229376, O_F2 = 491520;

    // ---- weight prep (every call; static content) ----
    wsplit_k<<<dim3(8, 8, 6),  256, 0, stream>>>(w_val,  Wh + O_VAL, Wl + O_VAL, 256, 256,  65536, WL);
    wsplit_k<<<dim3(8, 8, 6),  256, 0, stream>>>(w_off,  Wh + O_OFF, Wl + O_OFF, 256, 256,  65536, WL);
    wsplit_k<<<dim3(4, 8, 6),  256, 0, stream>>>(w_attn, Wh + O_ATT, Wl + O_ATT, 256, 128,  32768, WL);
    wsplit_k<<<dim3(8, 8, 6),  256, 0, stream>>>(w_out,  Wh + O_OUT, Wl + O_OUT, 256, 256,  65536, WL);
    wsplit_k<<<dim3(32, 8, 6), 256, 0, stream>>>(w_ffn1, Wh + O_F1,  Wl + O_F1,  256, 1024, 262144, WL);
    wsplit_k<<<dim3(8, 32, 6), 256, 0, stream>>>(w_ffn2, Wh + O_F2,  Wl + O_F2,  1024, 256, 262144, WL);
    boa_k<<<dim3(6), dim3(384), 0, stream>>>(b_off, b_attn, boa);

    const int HWs[4] = {7600, 1900, 475, 130};
    const int STt[4] = {0, 7600, 9500, 9975};
    for (int l = 0; l < 4; ++l) {
        dim3 g(HWs[l], BATCH);
        flatten_k<<<g, 256, 0, stream>>>(src_in[l], pos_in[l], lvl + l * 256,
                                         src, pos, HWs[l], STt[l]);
    }

    const int MB = (NTOK + 127) / 128;   // 158
    const int LNB = (NTOK + 3) / 4;      // 5053
    dim3 blk(256);

    for (int i = 0; i < NLAYERS; ++i) {
        const unsigned short* whL = Wh + (size_t)i * WL;
        const unsigned short* wlL = Wl + (size_t)i * WL;
        const float* bv  = b_val  + (size_t)i * 256;
        const float* bou = b_out  + (size_t)i * 256;
        const float* l1g = ln1_g  + (size_t)i * 256;
        const float* l1b = ln1_b  + (size_t)i * 256;
        const float* bf1 = b_ffn1 + (size_t)i * 1024;
        const float* bf2 = b_ffn2 + (size_t)i * 256;
        const float* l2g = ln2_g  + (size_t)i * 256;
        const float* l2b = ln2_b  + (size_t)i * 256;

        // value = src @ w_val + b_val  -> valb (bf16)
        gemm_mfma<false, false, false, false, true><<<dim3(MB * 2), blk, 0, stream>>>(
            src, nullptr, whL + O_VAL, wlL + O_VAL, bv, nullptr, valb, NTOK, 256, 256, 2);
        // [off|attn] = (src+pos) @ [w_off|w_attn] + boa  (N=384 fused, f32)
        gemm_mfma<false, true, false, false, false><<<dim3(MB * 3), blk, 0, stream>>>(
            src, pos, whL + O_OFF, wlL + O_OFF, boa + (size_t)i * 384, nullptr,
            oab, NTOK, 384, 256, 3);
        // deformable sampling -> samp (bf16)
        sample_k<<<dim3(LQ, BATCH), blk, 0, stream>>>(valb, oab, samp);
        // attn_out = samp @ w_out + b_out + src -> preln (f32); A bf16 2-pass
        gemm_mfma<true, false, false, true, false><<<dim3(MB * 2), blk, 0, stream>>>(
            samp, nullptr, whL + O_OUT, wlL + O_OUT, bou, src, preln, NTOK, 256, 256, 2);
        // LN1 -> src
        ln_k<<<dim3(LNB), blk, 0, stream>>>(preln, l1g, l1b, src, NTOK);
        // ffn1 = relu(src @ w_ffn1 + b_ffn1) -> ffnb (bf16)
        gemm_mfma<false, false, true, false, true><<<dim3(MB * 8), blk, 0, stream>>>(
            src, nullptr, whL + O_F1, wlL + O_F1, bf1, nullptr, ffnb, NTOK, 1024, 256, 8);
        // ffn2 = ffnb @ w_ffn2 + b_ffn2 + src -> preln (f32); A bf16 2-pass
        gemm_mfma<true, false, false, true, false><<<dim3(MB * 2), blk, 0, stream>>>(
            ffnb, nullptr, whL + O_F2, wlL + O_F2, bf2, src, preln, NTOK, 256, 1024, 2);
        // LN2 -> src (or d_out on last layer)
        float* dst = (i == NLAYERS - 1) ? (float*)d_out : src;
        ln_k<<<dim3(LNB), blk, 0, stream>>>(preln, l2g, l2b, dst, NTOK);
    }
}